// Round 7
// baseline (682.739 us; speedup 1.0000x reference)
//
#include <hip/hip_runtime.h>

#define NROWS 32768   // B*T
#define PD    512     // P_DIM
#define NCB   8       // NC
#define CSZ   256     // CS
#define TOTD  2048    // TOT
#define SIN   1792    // SELF_IN / SELF_OUT

typedef float floatx4  __attribute__((ext_vector_type(4)));
typedef float floatx16 __attribute__((ext_vector_type(16)));
typedef int   intx4    __attribute__((ext_vector_type(4)));
typedef int   intx8    __attribute__((ext_vector_type(8)));

__device__ __forceinline__ float bf2f(unsigned int h) {
    return __uint_as_float(h << 16);
}
__device__ __forceinline__ unsigned short f2bf(float f) {
    unsigned int u = __float_as_uint(f);
    u += 0x7FFFu + ((u >> 16) & 1u);
    return (unsigned short)(u >> 16);
}
// f32 -> fp8 e4m3 (single value, RNE, saturating)
__device__ __forceinline__ unsigned char f2fp8(float v) {
    int p = __builtin_amdgcn_cvt_pk_fp8_f32(v, v, 0, false);
    return (unsigned char)(p & 0xFF);
}

// async global->LDS, 16B per lane; LDS dest = wave-uniform base + lane*16
__device__ __forceinline__ void gload16(const unsigned char* g, unsigned char* l) {
    __builtin_amdgcn_global_load_lds(
        (const __attribute__((address_space(1))) void*)g,
        (__attribute__((address_space(3))) void*)l, 16, 0, 0);
}

// MFMA 32x32x64 f8f6f4 (cbsz=blgp=0 => e4m3 x e4m3), acc pinned to AGPRs so
// acc regs stay out of the arch-VGPR budget (round-2/3 spill lesson).
#define MFMA64(ACC, A, B)                                                     \
    asm volatile("v_mfma_f32_32x32x64_f8f6f4 %0, %1, %2, %0"                  \
                 : "+a"(ACC) : "v"(A), "v"(B))

#define SBAR() asm volatile("s_barrier" ::: "memory")

// ---------------- f32 -> fp8 conversion (8 elems/thread) ----------------
__global__ __launch_bounds__(256) void k_cvt8(const float* __restrict__ in,
                                              unsigned char* __restrict__ out,
                                              float scale, int n8) {
    int i = blockIdx.x * 256 + threadIdx.x;
    if (i >= n8) return;
    float4 a = ((const float4*)in)[2 * i];
    float4 b = ((const float4*)in)[2 * i + 1];
    int p0 = __builtin_amdgcn_cvt_pk_fp8_f32(a.x * scale, a.y * scale, 0, false);
    p0     = __builtin_amdgcn_cvt_pk_fp8_f32(a.z * scale, a.w * scale, p0, true);
    int p1 = __builtin_amdgcn_cvt_pk_fp8_f32(b.x * scale, b.y * scale, 0, false);
    p1     = __builtin_amdgcn_cvt_pk_fp8_f32(b.z * scale, b.w * scale, p1, true);
    int2 o; o.x = p0; o.y = p1;
    ((int2*)out)[i] = o;
}

// -------- transpose linear_self (1792x1792) f32 -> bf16, LSTb[in][out] --------
__global__ __launch_bounds__(256) void k_tb(const float* __restrict__ in,
                                            unsigned short* __restrict__ out) {
    __shared__ float t[32][33];
    int bx = blockIdx.x * 32, by = blockIdx.y * 32;
    int tx = threadIdx.x & 31, ty = threadIdx.x >> 5;
#pragma unroll
    for (int j = 0; j < 32; j += 8)
        t[ty + j][tx] = in[(size_t)(by + ty + j) * SIN + bx + tx];
    __syncthreads();
#pragma unroll
    for (int j = 0; j < 32; j += 8)
        out[(size_t)(bx + ty + j) * SIN + by + tx] = f2bf(t[tx][ty + j]);
}

// FAT-TILE GEMM (round-7): 256x128 block tile, 256 thr / 4 waves, wave tile
// 128x64 = 8 MFMA/iter (acc 128 AGPR pinned). Keeps the PROVEN round-4
// skeleton: triple buffer, ONE barrier + counted vmcnt per K-iter, prefetch
// distance 2. Halves block-iters vs round-4 (fixed ~4000cy rendezvous cost
// per iter-slot dominates; fewer slots = less total stall).
//
// LDS buffer (24KB): A = 8 tiles (256 rows) at +0, B = 4 tiles (128 cols) at
// +16384. Tile layout: [granule g (64)][32B]; granule g holds row sigma(g)&31
// (sigma(g)=g^((g&12)>>2), involution), k bytes (g>>5)*32..+31.
// Staging (6 gload16/wave/iter): wave w stages A tiles 2w,2w+1 (both khalves)
// + B tile w (both khalves): src row = base + sigma32(i>>1), koff = h*32 +
// (i&1)*16; dst = tilebase + h*1024 + i*16.
// Read: lane l octet at tilebase + ((l<<5) ^ ((l&12)<<3))  (two b128).
// vmcnt(6) per iter: drains tile i's 6 gloads, leaves tile i+1's in flight.
//
// XCD swizzle: grid 2048 (%8==0), swz = (bid&7)*256 + (bid>>3) -> each XCD
// gets 256 consecutive logical blocks = 2 B-panels (512KB, L2-resident).
//
// MFMA 32x32x64 fragment: lane l -> row/col = l&31, k = (l>>5)*32 + byte.
// C/D: col = l&31, row = (r&3) + 8*(r>>2) + 4*(l>>5), r in [0,16).

// ---------------- GEMM1 (fp8): Hraw8 = fp8(8 * (pred @ W1^T + b1)) ----------------
__global__ __launch_bounds__(256)
void k_gemm1(const unsigned char* __restrict__ A,
             const unsigned char* __restrict__ Bw,
             const float* __restrict__ bias,
             unsigned char* __restrict__ Out) {
    const int K = PD;
    __shared__ __align__(16) unsigned char S[3 * 24576];

    const int tid  = threadIdx.x;
    const int lane = tid & 63;
    const int w    = tid >> 6;            // 0..3
    const int wm   = (w >> 1) << 7;       // 0/128
    const int wn   = (w & 1) << 6;        // 0/64
    const int swz  = (blockIdx.x & 7) * 256 + (blockIdx.x >> 3);
    const int row0 = (swz & 127) << 8;
    const int col0 = (swz >> 7) << 7;

    floatx16 a00 = 0.f, a01 = 0.f, a10 = 0.f, a11 = 0.f;
    floatx16 a20 = 0.f, a21 = 0.f, a30 = 0.f, a31 = 0.f;

    const int gran = lane >> 1;
    const int sig  = gran ^ ((gran & 12) >> 2);
    const unsigned char* Ag = A  + (size_t)(row0 + (w << 6) + sig) * K + ((lane & 1) << 4);
    const unsigned char* Bg = Bw + (size_t)(col0 + (w << 5) + sig) * K + ((lane & 1) << 4);

    auto stage = [&](int buf, int k0) {
        unsigned char* d = S + buf * 24576;
        gload16(Ag + k0,              d + (w << 12));
        gload16(Ag + k0 + 32,         d + (w << 12) + 1024);
        gload16(Ag + k0 + 32 * K,     d + (w << 12) + 2048);
        gload16(Ag + k0 + 32 * K + 32,d + (w << 12) + 3072);
        gload16(Bg + k0,              d + 16384 + (w << 11));
        gload16(Bg + k0 + 32,         d + 16384 + (w << 11) + 1024);
    };

    const int ro = (lane << 5) ^ ((lane & 12) << 3);

    auto compute = [&](int cbuf) {
        const unsigned char* base = S + cbuf * 24576;
        const unsigned char* Ab = base + ((w >> 1) << 13) + ro;
        const unsigned char* Bb = base + 16384 + ((w & 1) << 12) + ro;
        intx8 A0 = *(const intx8*)Ab;
        intx8 A1 = *(const intx8*)(Ab + 2048);
        intx8 A2 = *(const intx8*)(Ab + 4096);
        intx8 A3 = *(const intx8*)(Ab + 6144);
        intx8 B0 = *(const intx8*)Bb;
        intx8 B1 = *(const intx8*)(Bb + 2048);
        MFMA64(a00, A0, B0); MFMA64(a01, A0, B1);
        MFMA64(a10, A1, B0); MFMA64(a11, A1, B1);
        MFMA64(a20, A2, B0); MFMA64(a21, A2, B1);
        MFMA64(a30, A3, B0); MFMA64(a31, A3, B1);
    };

    stage(0, 0);
    stage(1, 64);

    const int NI = K / 64;   // 8
    int cb = 0, nb = 2;
    for (int i = 0; i < NI - 1; ++i) {
        asm volatile("s_waitcnt vmcnt(6)" ::: "memory");
        SBAR();
        if (i + 2 < NI) stage(nb, (i + 2) * 64);
        compute(cb);
        cb = (cb + 1 == 3) ? 0 : cb + 1;
        nb = (nb + 1 == 3) ? 0 : nb + 1;
    }
    asm volatile("s_waitcnt vmcnt(0)" ::: "memory");
    SBAR();
    compute(cb);
    asm volatile("s_nop 7\n\ts_nop 7\n\ts_nop 7" ::: "memory");

    // epilogue: hidden = acc/16 + b1; store fp8(8*hidden)
    const int l31  = lane & 31;
    const int half = lane >> 5;
    const float bc0 = bias[col0 + wn + l31];
    const float bc1 = bias[col0 + wn + 32 + l31];
    auto epi = [&](const floatx16& Aa, const floatx16& Ab2, int jrow) {
        const int col = col0 + wn + l31;
#pragma unroll
        for (int r = 0; r < 16; ++r) {
            const int row = row0 + wm + jrow + (r & 3) + ((r >> 2) << 3) + (half << 2);
            Out[(size_t)row * TOTD + col]      = f2fp8((Aa[r]  * 0.0625f + bc0) * 8.f);
            Out[(size_t)row * TOTD + col + 32] = f2fp8((Ab2[r] * 0.0625f + bc1) * 8.f);
        }
    };
    epi(a00, a01, 0);
    epi(a10, a11, 32);
    epi(a20, a21, 64);
    epi(a30, a31, 96);
}

// -------- fused: self-gather + relu + LayerNorm; fp8 in (x8) -> fp8 out (x8) --------
__global__ __launch_bounds__(256) void k_ln(const unsigned char* __restrict__ Hraw8,
                                            unsigned char* __restrict__ H8,
                                            const unsigned short* __restrict__ LSTb,
                                            const int* __restrict__ idx,
                                            const float* __restrict__ gamma,
                                            const float* __restrict__ beta) {
    const int row = blockIdx.x;
    const int tid = threadIdx.x;
    __shared__ int sidx[8];
    __shared__ float ws4[4], wss4[4];
    if (tid < 8) sidx[tid] = idx[(size_t)row * NCB + tid];

    uint2 w = ((const uint2*)(Hraw8 + (size_t)row * TOTD))[tid];
    float x[8];
    x[0] = __builtin_amdgcn_cvt_f32_fp8(w.x, 0) * 0.125f;
    x[1] = __builtin_amdgcn_cvt_f32_fp8(w.x, 1) * 0.125f;
    x[2] = __builtin_amdgcn_cvt_f32_fp8(w.x, 2) * 0.125f;
    x[3] = __builtin_amdgcn_cvt_f32_fp8(w.x, 3) * 0.125f;
    x[4] = __builtin_amdgcn_cvt_f32_fp8(w.y, 0) * 0.125f;
    x[5] = __builtin_amdgcn_cvt_f32_fp8(w.y, 1) * 0.125f;
    x[6] = __builtin_amdgcn_cvt_f32_fp8(w.y, 2) * 0.125f;
    x[7] = __builtin_amdgcn_cvt_f32_fp8(w.y, 3) * 0.125f;
    __syncthreads();

    const int gt = tid >> 5;
#pragma unroll
    for (int c = 0; c < 7; ++c) {
        if (c < gt) {
            int ic = sidx[c];
            if (ic >= 0) {
                uint4 v = *(const uint4*)(LSTb + (size_t)(c * CSZ + ic) * SIN + (tid * 8 - CSZ));
                x[0] += bf2f(v.x & 0xFFFF); x[1] += bf2f(v.x >> 16);
                x[2] += bf2f(v.y & 0xFFFF); x[3] += bf2f(v.y >> 16);
                x[4] += bf2f(v.z & 0xFFFF); x[5] += bf2f(v.z >> 16);
                x[6] += bf2f(v.w & 0xFFFF); x[7] += bf2f(v.w >> 16);
            }
        }
    }
#pragma unroll
    for (int e = 0; e < 8; ++e) x[e] = fmaxf(x[e], 0.f);

    float s = 0.f, ss = 0.f;
#pragma unroll
    for (int e = 0; e < 8; ++e) { s += x[e]; ss += x[e] * x[e]; }
#pragma unroll
    for (int o = 32; o; o >>= 1) { s += __shfl_xor(s, o); ss += __shfl_xor(ss, o); }
    if ((tid & 63) == 0) { ws4[tid >> 6] = s; wss4[tid >> 6] = ss; }
    __syncthreads();
    s  = ws4[0] + ws4[1] + ws4[2] + ws4[3];
    ss = wss4[0] + wss4[1] + wss4[2] + wss4[3];
    const float mu = s * (1.f / TOTD);
    const float var = ss * (1.f / TOTD) - mu * mu;
    const float rstd = rsqrtf(var + 1e-5f);
    float y[8];
#pragma unroll
    for (int e = 0; e < 8; ++e) {
        int col = tid * 8 + e;
        y[e] = ((x[e] - mu) * rstd * gamma[col] + beta[col]) * 8.f;   // H scale 8
    }
    int p0 = __builtin_amdgcn_cvt_pk_fp8_f32(y[0], y[1], 0, false);
    p0     = __builtin_amdgcn_cvt_pk_fp8_f32(y[2], y[3], p0, true);
    int p1 = __builtin_amdgcn_cvt_pk_fp8_f32(y[4], y[5], 0, false);
    p1     = __builtin_amdgcn_cvt_pk_fp8_f32(y[6], y[7], p1, true);
    int2 o; o.x = p0; o.y = p1;
    ((int2*)(H8 + (size_t)row * TOTD))[tid] = o;
}

// ------- GEMM2 (fp8): 256x128 fat tile, round-4 skeleton + partial-softmax -------
__global__ __launch_bounds__(256)
void k_gemm2(const unsigned char* __restrict__ H,
             const unsigned char* __restrict__ W2,
             const float* __restrict__ b2,
             const int* __restrict__ idx,
             float* __restrict__ pm_,
             float* __restrict__ ps_,
             float* __restrict__ pt_) {
    const int K = TOTD;
    __shared__ __align__(16) unsigned char S[3 * 24576];
    __shared__ int tidx[256];

    const int tid  = threadIdx.x;
    const int lane = tid & 63;
    const int w    = tid >> 6;
    const int wm   = (w >> 1) << 7;
    const int wn   = (w & 1) << 6;
    const int swz  = (blockIdx.x & 7) * 256 + (blockIdx.x >> 3);
    const int row0 = (swz & 127) << 8;
    const int col0 = (swz >> 7) << 7;
    const int g    = col0 >> 8;

    floatx16 a00 = 0.f, a01 = 0.f, a10 = 0.f, a11 = 0.f;
    floatx16 a20 = 0.f, a21 = 0.f, a30 = 0.f, a31 = 0.f;

    tidx[tid] = idx[(size_t)(row0 + tid) * NCB + g];

    const int gran = lane >> 1;
    const int sig  = gran ^ ((gran & 12) >> 2);
    const unsigned char* Ag = H  + (size_t)(row0 + (w << 6) + sig) * K + ((lane & 1) << 4);
    const unsigned char* Bg = W2 + (size_t)(col0 + (w << 5) + sig) * K + ((lane & 1) << 4);

    auto stage = [&](int buf, int k0) {
        unsigned char* d = S + buf * 24576;
        gload16(Ag + k0,               d + (w << 12));
        gload16(Ag + k0 + 32,          d + (w << 12) + 1024);
        gload16(Ag + k0 + 32 * K,      d + (w << 12) + 2048);
        gload16(Ag + k0 + 32 * K + 32, d + (w << 12) + 3072);
        gload16(Bg + k0,               d + 16384 + (w << 11));
        gload16(Bg + k0 + 32,          d + 16384 + (w << 11) + 1024);
    };

    const int ro = (lane << 5) ^ ((lane & 12) << 3);

    auto compute = [&](int cbuf) {
        const unsigned char* base = S + cbuf * 24576;
        const unsigned char* Ab = base + ((w >> 1) << 13) + ro;
        const unsigned char* Bb = base + 16384 + ((w & 1) << 12) + ro;
        intx8 A0 = *(const intx8*)Ab;
        intx8 A1 = *(const intx8*)(Ab + 2048);
        intx8 A2 = *(const intx8*)(Ab + 4096);
        intx8 A3 = *(const intx8*)(Ab + 6144);
        intx8 B0 = *(const intx8*)Bb;
        intx8 B1 = *(const intx8*)(Bb + 2048);
        MFMA64(a00, A0, B0); MFMA64(a01, A0, B1);
        MFMA64(a10, A1, B0); MFMA64(a11, A1, B1);
        MFMA64(a20, A2, B0); MFMA64(a21, A2, B1);
        MFMA64(a30, A3, B0); MFMA64(a31, A3, B1);
    };

    stage(0, 0);
    stage(1, 64);

    const int NI = K / 64;   // 32
    int cb = 0, nb = 2;
    for (int i = 0; i < NI - 1; ++i) {
        asm volatile("s_waitcnt vmcnt(6)" ::: "memory");
        SBAR();
        if (i + 2 < NI) stage(nb, (i + 2) * 64);
        compute(cb);
        cb = (cb + 1 == 3) ? 0 : cb + 1;
        nb = (nb + 1 == 3) ? 0 : nb + 1;
    }
    asm volatile("s_waitcnt vmcnt(0)" ::: "memory");
    SBAR();
    compute(cb);
    asm volatile("s_nop 7\n\ts_nop 7\n\ts_nop 7" ::: "memory");

    // ---- epilogue: per-row partials over 32-col slots ----
    const int l31  = lane & 31;
    const int half = lane >> 5;
    const int slotbase = (col0 + wn) >> 5;
    const int coff = (col0 & 255) + wn;
    const float bc0 = b2[col0 + wn + l31];
    const float bc1 = b2[col0 + wn + 32 + l31];

    auto epi = [&](const floatx16& Aa, int jrow, int kk, float bc) {
#pragma unroll
        for (int r = 0; r < 16; ++r) {
            const int lrow = wm + jrow + (r & 3) + ((r >> 2) << 3) + (half << 2);
            const int ic   = tidx[lrow];
            float v = Aa[r] * 0.0078125f + bc;
            float mm = v;
            float tv = (ic >= 0 && l31 == ic - coff - (kk << 5)) ? v : 0.f;
#pragma unroll
            for (int o = 1; o < 32; o <<= 1) mm = fmaxf(mm, __shfl_xor(mm, o));
            float sv = __expf(v - mm);
#pragma unroll
            for (int o = 1; o < 32; o <<= 1) { sv += __shfl_xor(sv, o); tv += __shfl_xor(tv, o); }
            if (l31 == 0) {
                const int row = row0 + lrow;
                pm_[(size_t)(slotbase + kk) * NROWS + row] = mm;
                ps_[(size_t)(slotbase + kk) * NROWS + row] = sv;
                pt_[(size_t)(slotbase + kk) * NROWS + row] = tv;
            }
        }
    };
    epi(a00, 0, 0, bc0);  epi(a01, 0, 1, bc1);
    epi(a10, 32, 0, bc0); epi(a11, 32, 1, bc1);
    epi(a20, 64, 0, bc0); epi(a21, 64, 1, bc1);
    epi(a30, 96, 0, bc0); epi(a31, 96, 1, bc1);
}

// ------- combine: merge 8 slots per (row, group), accumulate logprob + count -------
__global__ __launch_bounds__(256) void k_comb(const float* __restrict__ pm_,
                                              const float* __restrict__ ps_,
                                              const float* __restrict__ pt_,
                                              const int* __restrict__ idx,
                                              float* __restrict__ out) {
    const int i   = blockIdx.x * 256 + threadIdx.x;
    const int row = i & (NROWS - 1);
    const int g   = i >> 15;
    const int ic  = idx[(size_t)row * NCB + g];
    float lp = 0.f, cnt = 0.f;
    if (ic >= 0) {
        const size_t b = (size_t)(g * 8) * NROWS + row;
        float m[8], s[8], t = 0.f;
        float mm = -3.4e38f;
#pragma unroll
        for (int k = 0; k < 8; ++k) {
            m[k] = pm_[b + (size_t)k * NROWS];
            s[k] = ps_[b + (size_t)k * NROWS];
            t   += pt_[b + (size_t)k * NROWS];
            mm = fmaxf(mm, m[k]);
        }
        float Z = 0.f;
#pragma unroll
        for (int k = 0; k < 8; ++k) Z += s[k] * __expf(m[k] - mm);
        lp = t - (mm + __logf(Z));
        cnt = 1.f;
    }
#pragma unroll
    for (int o = 1; o < 64; o <<= 1) { lp += __shfl_xor(lp, o); cnt += __shfl_xor(cnt, o); }
    __shared__ float wred[8];
    const int lane = threadIdx.x & 63, wave = threadIdx.x >> 6;
    if (lane == 0) { wred[wave] = lp; wred[4 + wave] = cnt; }
    __syncthreads();
    if (threadIdx.x == 0) {
        atomicAdd(&out[0], wred[0] + wred[1] + wred[2] + wred[3]);
        atomicAdd(&out[1], wred[4] + wred[5] + wred[6] + wred[7]);
    }
}

extern "C" void kernel_launch(void* const* d_in, const int* in_sizes, int n_in,
                              void* d_out, int out_size, void* d_ws, size_t ws_size,
                              hipStream_t stream) {
    const float* predictor = (const float*)d_in[0];
    const int*   cbidx     = (const int*)d_in[1];
    const float* W1        = (const float*)d_in[2];
    const float* b1        = (const float*)d_in[3];
    const float* LS        = (const float*)d_in[4];
    const float* gamma     = (const float*)d_in[5];
    const float* beta      = (const float*)d_in[6];
    const float* W2        = (const float*)d_in[7];
    const float* b2        = (const float*)d_in[8];
    float* out = (float*)d_out;

    char* ws = (char*)d_ws;
    size_t off = 0;
    auto alloc = [&](size_t bytes) {
        char* p = ws + off;
        off += (bytes + 255) & ~(size_t)255;
        return p;
    };
    unsigned char* Hraw8 = (unsigned char*)alloc((size_t)NROWS * TOTD);   // dead after k_ln -> pm/ps/pt alias
    unsigned char* R2    = (unsigned char*)alloc((size_t)NROWS * TOTD);   // pred8+W1_8, then H8
    unsigned char* W2_8  = (unsigned char*)alloc((size_t)TOTD * TOTD);
    unsigned short* LSTb = (unsigned short*)alloc((size_t)SIN * SIN * 2);

    unsigned char* pred8 = R2;
    unsigned char* W1_8  = R2 + (size_t)NROWS * PD;
    unsigned char* H8    = R2;
    float* pm_ = (float*)Hraw8;
    float* ps_ = pm_ + (size_t)64 * NROWS;
    float* pt_ = ps_ + (size_t)64 * NROWS;

    hipMemsetAsync(d_out, 0, 2 * sizeof(float), stream);

    k_cvt8<<<NROWS * PD / 8 / 256, 256, 0, stream>>>(predictor, pred8, 1.f, NROWS * PD / 8);
    k_cvt8<<<TOTD * PD / 8 / 256, 256, 0, stream>>>(W1, W1_8, 16.f, TOTD * PD / 8);
    k_cvt8<<<TOTD * TOTD / 8 / 256, 256, 0, stream>>>(W2, W2_8, 16.f, TOTD * TOTD / 8);
    k_tb<<<dim3(SIN / 32, SIN / 32), 256, 0, stream>>>(LS, LSTb);

    k_gemm1<<<2048, 256, 0, stream>>>(pred8, W1_8, b1, Hraw8);
    k_ln<<<NROWS, 256, 0, stream>>>(Hraw8, H8, LSTb, cbidx, gamma, beta);
    k_gemm2<<<2048, 256, 0, stream>>>(H8, W2_8, b2, cbidx, pm_, ps_, pt_);
    k_comb<<<NROWS * NCB / 256, 256, 0, stream>>>(pm_, ps_, pt_, cbidx, out);
}

// Round 8
// 658.794 us; speedup vs baseline: 1.0363x; 1.0363x over previous
//
#include <hip/hip_runtime.h>

#define NROWS 32768   // B*T
#define PD    512     // P_DIM
#define NCB   8       // NC
#define CSZ   256     // CS
#define TOTD  2048    // TOT
#define SIN   1792    // SELF_IN / SELF_OUT

typedef float floatx4  __attribute__((ext_vector_type(4)));
typedef float floatx16 __attribute__((ext_vector_type(16)));
typedef int   intx4    __attribute__((ext_vector_type(4)));
typedef int   intx8    __attribute__((ext_vector_type(8)));

__device__ __forceinline__ float bf2f(unsigned int h) {
    return __uint_as_float(h << 16);
}
__device__ __forceinline__ unsigned short f2bf(float f) {
    unsigned int u = __float_as_uint(f);
    u += 0x7FFFu + ((u >> 16) & 1u);
    return (unsigned short)(u >> 16);
}
// f32 -> fp8 e4m3 (single value, RNE, saturating)
__device__ __forceinline__ unsigned char f2fp8(float v) {
    int p = __builtin_amdgcn_cvt_pk_fp8_f32(v, v, 0, false);
    return (unsigned char)(p & 0xFF);
}

// async global->LDS, 16B per lane; LDS dest = wave-uniform base + lane*16
__device__ __forceinline__ void gload16(const unsigned char* g, unsigned char* l) {
    __builtin_amdgcn_global_load_lds(
        (const __attribute__((address_space(1))) void*)g,
        (__attribute__((address_space(3))) void*)l, 16, 0, 0);
}

// MFMA 32x32x64 f8f6f4 (cbsz=blgp=0 => e4m3 x e4m3), acc pinned to AGPRs so
// acc regs stay out of the arch-VGPR budget (round-2/3 spill lesson).
#define MFMA64(ACC, A, B)                                                     \
    asm volatile("v_mfma_f32_32x32x64_f8f6f4 %0, %1, %2, %0"                  \
                 : "+a"(ACC) : "v"(A), "v"(B))

#define SBAR() asm volatile("s_barrier" ::: "memory")

// two ds_read_b128 512B apart -> one v8i32 MFMA operand (concat; regalloc
// coalesces the quads into adjacent registers when consumed immediately)
__device__ __forceinline__ intx8 ld_op(const unsigned char* p) {
    intx4 lo = *(const intx4*)p;
    intx4 hi = *(const intx4*)(p + 512);
    return __builtin_shufflevector(lo, hi, 0, 1, 2, 3, 4, 5, 6, 7);
}

// ---------------- f32 -> fp8 conversion (8 elems/thread) ----------------
__global__ __launch_bounds__(256) void k_cvt8(const float* __restrict__ in,
                                              unsigned char* __restrict__ out,
                                              float scale, int n8) {
    int i = blockIdx.x * 256 + threadIdx.x;
    if (i >= n8) return;
    float4 a = ((const float4*)in)[2 * i];
    float4 b = ((const float4*)in)[2 * i + 1];
    int p0 = __builtin_amdgcn_cvt_pk_fp8_f32(a.x * scale, a.y * scale, 0, false);
    p0     = __builtin_amdgcn_cvt_pk_fp8_f32(a.z * scale, a.w * scale, p0, true);
    int p1 = __builtin_amdgcn_cvt_pk_fp8_f32(b.x * scale, b.y * scale, 0, false);
    p1     = __builtin_amdgcn_cvt_pk_fp8_f32(b.z * scale, b.w * scale, p1, true);
    int2 o; o.x = p0; o.y = p1;
    ((int2*)out)[i] = o;
}

// -------- transpose linear_self (1792x1792) f32 -> bf16, LSTb[in][out] --------
__global__ __launch_bounds__(256) void k_tb(const float* __restrict__ in,
                                            unsigned short* __restrict__ out) {
    __shared__ float t[32][33];
    int bx = blockIdx.x * 32, by = blockIdx.y * 32;
    int tx = threadIdx.x & 31, ty = threadIdx.x >> 5;
#pragma unroll
    for (int j = 0; j < 32; j += 8)
        t[ty + j][tx] = in[(size_t)(by + ty + j) * SIN + bx + tx];
    __syncthreads();
#pragma unroll
    for (int j = 0; j < 32; j += 8)
        out[(size_t)(bx + ty + j) * SIN + by + tx] = f2bf(t[tx][ty + j]);
}

// ROUND-4 SKELETON (proven best: 285us gemm2) with CONFLICT-FREE LDS planes.
// 128x128 tile, 256 thr / 4 waves, wave tile 64x64 (2x2 MFMA, acc 64 AGPR),
// TRIPLE buffer, ONE barrier + vmcnt(4) per K-iter, prefetch distance 2.
//
// LDS tile (2KB, 32 rows x 64 k-bytes): [kq (4)][row (32)][16B],
//   byte(row, kb) = (kb>>4)*512 + row*16 + (kb&15).
// Read (lane l: row l&31, kq pair 2*(l>>5)): lo at (l>>5)*1024 + (l&31)*16,
//   hi at +512. 16-lane phase hits 16B-slots (l&7)+... covering all 8 slots
//   => conflict-free (r4 layout was 4-way: first b128 even-slots-only;
//   r5-vs-r4 counter scaling proved conflicts are read-side).
// Staging per wave w (tile w of A and of B, 2 gloads each, k0 window 64B):
//   lane i -> src row = 32w + (i&31), kbyte = k0 + c*32 + (i>>5)*16,
//   dst = buf + w*2048 + c*1024 + i*16  (linear, as gload16 requires).
// vmcnt(4): drains tile i's 4 gloads, keeps tile i+1's 4 in flight.
//
// MFMA 32x32x64 fragment: lane l -> row/col = l&31, k = (l>>5)*32 + byte.
// C/D: col = l&31, row = (r&3) + 8*(r>>2) + 4*(l>>5), r in [0,16).

// ---------------- GEMM1 (fp8): Hraw8 = fp8(8 * (pred @ W1^T + b1)) ----------------
__global__ __launch_bounds__(256)
void k_gemm1(const unsigned char* __restrict__ A,
             const unsigned char* __restrict__ Bw,
             const float* __restrict__ bias,
             unsigned char* __restrict__ Out) {
    const int K = PD;
    __shared__ __align__(16) unsigned char As[3 * 8192];
    __shared__ __align__(16) unsigned char Bs[3 * 8192];

    const int tid  = threadIdx.x;
    const int lane = tid & 63;
    const int w    = tid >> 6;
    const int wm = (w >> 1) << 6;
    const int wn = (w & 1) << 6;
    const int bid  = blockIdx.x;
    const int row0 = (bid & 255) << 7;
    const int col0 = (bid >> 8) << 7;

    floatx16 acc00 = 0.f, acc01 = 0.f, acc10 = 0.f, acc11 = 0.f;

    const unsigned char* Ag = A  + (size_t)(row0 + (w << 5) + (lane & 31)) * K + ((lane >> 5) << 4);
    const unsigned char* Bg = Bw + (size_t)(col0 + (w << 5) + (lane & 31)) * K + ((lane >> 5) << 4);
    unsigned char* Al = As + w * 2048;
    unsigned char* Bl = Bs + w * 2048;

    auto stage = [&](int buf, int k0) {
        gload16(Ag + k0,      Al + buf * 8192);
        gload16(Ag + k0 + 32, Al + buf * 8192 + 1024);
        gload16(Bg + k0,      Bl + buf * 8192);
        gload16(Bg + k0 + 32, Bl + buf * 8192 + 1024);
    };

    stage(0, 0);
    stage(1, 64);

    const int rr = ((lane >> 5) << 10) + ((lane & 31) << 4);

    auto compute = [&](int cbuf) {
        const unsigned char* Ab = As + cbuf * 8192 + ((w >> 1) << 12) + rr;
        const unsigned char* Bb = Bs + cbuf * 8192 + ((w & 1) << 12) + rr;
        intx8 a0 = ld_op(Ab);
        intx8 a1 = ld_op(Ab + 2048);
        intx8 b0 = ld_op(Bb);
        intx8 b1 = ld_op(Bb + 2048);
        MFMA64(acc00, a0, b0);
        MFMA64(acc10, a1, b0);
        MFMA64(acc01, a0, b1);
        MFMA64(acc11, a1, b1);
    };

    const int NI = K / 64;   // 8
    int cb = 0, nb = 2;
    for (int i = 0; i < NI - 1; ++i) {
        asm volatile("s_waitcnt vmcnt(4)" ::: "memory");
        SBAR();
        if (i + 2 < NI) stage(nb, (i + 2) * 64);
        compute(cb);
        cb = (cb + 1 == 3) ? 0 : cb + 1;
        nb = (nb + 1 == 3) ? 0 : nb + 1;
    }
    asm volatile("s_waitcnt vmcnt(0)" ::: "memory");
    SBAR();
    compute(cb);
    asm volatile("s_nop 7\n\ts_nop 7\n\ts_nop 7" ::: "memory");

    // epilogue: hidden = acc/16 + b1; store fp8(8*hidden)
    const int l31  = lane & 31;
    const int half = lane >> 5;
    auto epi = [&](const floatx16& A0, const floatx16& A1, int mtoff) {
        const int col = col0 + wn + l31;
        const float bc0 = bias[col];
        const float bc1 = bias[col + 32];
#pragma unroll
        for (int r = 0; r < 16; ++r) {
            const int row = row0 + wm + mtoff + (r & 3) + ((r >> 2) << 3) + (half << 2);
            Out[(size_t)row * TOTD + col]      = f2fp8((A0[r] * 0.0625f + bc0) * 8.f);
            Out[(size_t)row * TOTD + col + 32] = f2fp8((A1[r] * 0.0625f + bc1) * 8.f);
        }
    };
    epi(acc00, acc01, 0);
    epi(acc10, acc11, 32);
}

// -------- fused: self-gather + relu + LayerNorm; fp8 in (x8) -> fp8 out (x8) --------
__global__ __launch_bounds__(256) void k_ln(const unsigned char* __restrict__ Hraw8,
                                            unsigned char* __restrict__ H8,
                                            const unsigned short* __restrict__ LSTb,
                                            const int* __restrict__ idx,
                                            const float* __restrict__ gamma,
                                            const float* __restrict__ beta) {
    const int row = blockIdx.x;
    const int tid = threadIdx.x;
    __shared__ int sidx[8];
    __shared__ float ws4[4], wss4[4];
    if (tid < 8) sidx[tid] = idx[(size_t)row * NCB + tid];

    uint2 w = ((const uint2*)(Hraw8 + (size_t)row * TOTD))[tid];
    float x[8];
    x[0] = __builtin_amdgcn_cvt_f32_fp8(w.x, 0) * 0.125f;
    x[1] = __builtin_amdgcn_cvt_f32_fp8(w.x, 1) * 0.125f;
    x[2] = __builtin_amdgcn_cvt_f32_fp8(w.x, 2) * 0.125f;
    x[3] = __builtin_amdgcn_cvt_f32_fp8(w.x, 3) * 0.125f;
    x[4] = __builtin_amdgcn_cvt_f32_fp8(w.y, 0) * 0.125f;
    x[5] = __builtin_amdgcn_cvt_f32_fp8(w.y, 1) * 0.125f;
    x[6] = __builtin_amdgcn_cvt_f32_fp8(w.y, 2) * 0.125f;
    x[7] = __builtin_amdgcn_cvt_f32_fp8(w.y, 3) * 0.125f;
    __syncthreads();

    const int gt = tid >> 5;
#pragma unroll
    for (int c = 0; c < 7; ++c) {
        if (c < gt) {
            int ic = sidx[c];
            if (ic >= 0) {
                uint4 v = *(const uint4*)(LSTb + (size_t)(c * CSZ + ic) * SIN + (tid * 8 - CSZ));
                x[0] += bf2f(v.x & 0xFFFF); x[1] += bf2f(v.x >> 16);
                x[2] += bf2f(v.y & 0xFFFF); x[3] += bf2f(v.y >> 16);
                x[4] += bf2f(v.z & 0xFFFF); x[5] += bf2f(v.z >> 16);
                x[6] += bf2f(v.w & 0xFFFF); x[7] += bf2f(v.w >> 16);
            }
        }
    }
#pragma unroll
    for (int e = 0; e < 8; ++e) x[e] = fmaxf(x[e], 0.f);

    float s = 0.f, ss = 0.f;
#pragma unroll
    for (int e = 0; e < 8; ++e) { s += x[e]; ss += x[e] * x[e]; }
#pragma unroll
    for (int o = 32; o; o >>= 1) { s += __shfl_xor(s, o); ss += __shfl_xor(ss, o); }
    if ((tid & 63) == 0) { ws4[tid >> 6] = s; wss4[tid >> 6] = ss; }
    __syncthreads();
    s  = ws4[0] + ws4[1] + ws4[2] + ws4[3];
    ss = wss4[0] + wss4[1] + wss4[2] + wss4[3];
    const float mu = s * (1.f / TOTD);
    const float var = ss * (1.f / TOTD) - mu * mu;
    const float rstd = rsqrtf(var + 1e-5f);
    float y[8];
#pragma unroll
    for (int e = 0; e < 8; ++e) {
        int col = tid * 8 + e;
        y[e] = ((x[e] - mu) * rstd * gamma[col] + beta[col]) * 8.f;   // H scale 8
    }
    int p0 = __builtin_amdgcn_cvt_pk_fp8_f32(y[0], y[1], 0, false);
    p0     = __builtin_amdgcn_cvt_pk_fp8_f32(y[2], y[3], p0, true);
    int p1 = __builtin_amdgcn_cvt_pk_fp8_f32(y[4], y[5], 0, false);
    p1     = __builtin_amdgcn_cvt_pk_fp8_f32(y[6], y[7], p1, true);
    int2 o; o.x = p0; o.y = p1;
    ((int2*)(H8 + (size_t)row * TOTD))[tid] = o;
}

// ------- GEMM2 (fp8): 128x128 tile, r4 skeleton + partial-softmax epilogue -------
__global__ __launch_bounds__(256)
void k_gemm2(const unsigned char* __restrict__ H,
             const unsigned char* __restrict__ W2,
             const float* __restrict__ b2,
             const int* __restrict__ idx,
             float* __restrict__ pm_,
             float* __restrict__ ps_,
             float* __restrict__ pt_) {
    const int K = TOTD;
    __shared__ __align__(16) unsigned char As[3 * 8192];
    __shared__ __align__(16) unsigned char Bs[3 * 8192];
    __shared__ int tidx[128];

    const int tid  = threadIdx.x;
    const int lane = tid & 63;
    const int w    = tid >> 6;
    const int wm = (w >> 1) << 6;
    const int wn = (w & 1) << 6;
    const int bid  = blockIdx.x;
    const int row0 = (bid & 255) << 7;
    const int col0 = (bid >> 8) << 7;
    const int g    = col0 >> 8;

    floatx16 acc00 = 0.f, acc01 = 0.f, acc10 = 0.f, acc11 = 0.f;

    if (tid < 128) tidx[tid] = idx[(size_t)(row0 + tid) * NCB + g];

    const unsigned char* Ag = H  + (size_t)(row0 + (w << 5) + (lane & 31)) * K + ((lane >> 5) << 4);
    const unsigned char* Bg = W2 + (size_t)(col0 + (w << 5) + (lane & 31)) * K + ((lane >> 5) << 4);
    unsigned char* Al = As + w * 2048;
    unsigned char* Bl = Bs + w * 2048;

    auto stage = [&](int buf, int k0) {
        gload16(Ag + k0,      Al + buf * 8192);
        gload16(Ag + k0 + 32, Al + buf * 8192 + 1024);
        gload16(Bg + k0,      Bl + buf * 8192);
        gload16(Bg + k0 + 32, Bl + buf * 8192 + 1024);
    };

    stage(0, 0);
    stage(1, 64);

    const int rr = ((lane >> 5) << 10) + ((lane & 31) << 4);

    auto compute = [&](int cbuf) {
        const unsigned char* Ab = As + cbuf * 8192 + ((w >> 1) << 12) + rr;
        const unsigned char* Bb = Bs + cbuf * 8192 + ((w & 1) << 12) + rr;
        intx8 a0 = ld_op(Ab);
        intx8 a1 = ld_op(Ab + 2048);
        intx8 b0 = ld_op(Bb);
        intx8 b1 = ld_op(Bb + 2048);
        MFMA64(acc00, a0, b0);
        MFMA64(acc10, a1, b0);
        MFMA64(acc01, a0, b1);
        MFMA64(acc11, a1, b1);
    };

    const int NI = K / 64;   // 32
    int cb = 0, nb = 2;
    for (int i = 0; i < NI - 1; ++i) {
        asm volatile("s_waitcnt vmcnt(4)" ::: "memory");
        SBAR();
        if (i + 2 < NI) stage(nb, (i + 2) * 64);
        compute(cb);
        cb = (cb + 1 == 3) ? 0 : cb + 1;
        nb = (nb + 1 == 3) ? 0 : nb + 1;
    }
    asm volatile("s_waitcnt vmcnt(0)" ::: "memory");
    SBAR();
    compute(cb);
    asm volatile("s_nop 7\n\ts_nop 7\n\ts_nop 7" ::: "memory");

    // ---- epilogue: per-row partials over this wave's 64-col window ----
    const int l31  = lane & 31;
    const int half = lane >> 5;
    const int slot = (col0 + wn) >> 6;   // 0..31
    const int coff = (col0 & 255) + wn;
    const float bc0 = b2[col0 + wn + l31];
    const float bc1 = b2[col0 + wn + 32 + l31];

    auto epi = [&](const floatx16& A0, const floatx16& A1, int mtoff) {
#pragma unroll
        for (int r = 0; r < 16; ++r) {
            const int lrow = wm + mtoff + (r & 3) + ((r >> 2) << 3) + (half << 2);
            const int ic   = tidx[lrow];
            const int tloc = ic - coff;
            float v0 = A0[r] * 0.0078125f + bc0;
            float v1 = A1[r] * 0.0078125f + bc1;
            float mm = fmaxf(v0, v1), tv = 0.f;
            if (ic >= 0) {
                if (l31 == tloc)      tv += v0;
                if (l31 + 32 == tloc) tv += v1;
            }
#pragma unroll
            for (int o = 1; o < 32; o <<= 1) mm = fmaxf(mm, __shfl_xor(mm, o));
            float sv = __expf(v0 - mm) + __expf(v1 - mm);
#pragma unroll
            for (int o = 1; o < 32; o <<= 1) { sv += __shfl_xor(sv, o); tv += __shfl_xor(tv, o); }
            if (l31 == 0) {
                const int row = row0 + lrow;
                pm_[(size_t)slot * NROWS + row] = mm;
                ps_[(size_t)slot * NROWS + row] = sv;
                pt_[(size_t)slot * NROWS + row] = tv;
            }
        }
    };
    epi(acc00, acc01, 0);
    epi(acc10, acc11, 32);
}

// ------- combine: merge 4 slots per (row, group), accumulate logprob + count -------
__global__ __launch_bounds__(256) void k_comb(const float* __restrict__ pm_,
                                              const float* __restrict__ ps_,
                                              const float* __restrict__ pt_,
                                              const int* __restrict__ idx,
                                              float* __restrict__ out) {
    const int i   = blockIdx.x * 256 + threadIdx.x;
    const int row = i & (NROWS - 1);
    const int g   = i >> 15;
    const int ic  = idx[(size_t)row * NCB + g];
    float lp = 0.f, cnt = 0.f;
    if (ic >= 0) {
        const size_t b = (size_t)(g * 4) * NROWS + row;
        float m0 = pm_[b], m1 = pm_[b + NROWS], m2 = pm_[b + 2 * NROWS], m3 = pm_[b + 3 * NROWS];
        float mm = fmaxf(fmaxf(m0, m1), fmaxf(m2, m3));
        float Z = ps_[b] * __expf(m0 - mm) + ps_[b + NROWS] * __expf(m1 - mm)
                + ps_[b + 2 * NROWS] * __expf(m2 - mm) + ps_[b + 3 * NROWS] * __expf(m3 - mm);
        float t = pt_[b] + pt_[b + NROWS] + pt_[b + 2 * NROWS] + pt_[b + 3 * NROWS];
        lp = t - (mm + __logf(Z));
        cnt = 1.f;
    }
#pragma unroll
    for (int o = 1; o < 64; o <<= 1) { lp += __shfl_xor(lp, o); cnt += __shfl_xor(cnt, o); }
    __shared__ float wred[8];
    const int lane = threadIdx.x & 63, wave = threadIdx.x >> 6;
    if (lane == 0) { wred[wave] = lp; wred[4 + wave] = cnt; }
    __syncthreads();
    if (threadIdx.x == 0) {
        atomicAdd(&out[0], wred[0] + wred[1] + wred[2] + wred[3]);
        atomicAdd(&out[1], wred[4] + wred[5] + wred[6] + wred[7]);
    }
}

extern "C" void kernel_launch(void* const* d_in, const int* in_sizes, int n_in,
                              void* d_out, int out_size, void* d_ws, size_t ws_size,
                              hipStream_t stream) {
    const float* predictor = (const float*)d_in[0];
    const int*   cbidx     = (const int*)d_in[1];
    const float* W1        = (const float*)d_in[2];
    const float* b1        = (const float*)d_in[3];
    const float* LS        = (const float*)d_in[4];
    const float* gamma     = (const float*)d_in[5];
    const float* beta      = (const float*)d_in[6];
    const float* W2        = (const float*)d_in[7];
    const float* b2        = (const float*)d_in[8];
    float* out = (float*)d_out;

    char* ws = (char*)d_ws;
    size_t off = 0;
    auto alloc = [&](size_t bytes) {
        char* p = ws + off;
        off += (bytes + 255) & ~(size_t)255;
        return p;
    };
    unsigned char* Hraw8 = (unsigned char*)alloc((size_t)NROWS * TOTD);   // dead after k_ln -> pm/ps/pt alias
    unsigned char* R2    = (unsigned char*)alloc((size_t)NROWS * TOTD);   // pred8+W1_8, then H8
    unsigned char* W2_8  = (unsigned char*)alloc((size_t)TOTD * TOTD);
    unsigned short* LSTb = (unsigned short*)alloc((size_t)SIN * SIN * 2);

    unsigned char* pred8 = R2;
    unsigned char* W1_8  = R2 + (size_t)NROWS * PD;
    unsigned char* H8    = R2;
    float* pm_ = (float*)Hraw8;
    float* ps_ = pm_ + (size_t)32 * NROWS;
    float* pt_ = ps_ + (size_t)32 * NROWS;

    hipMemsetAsync(d_out, 0, 2 * sizeof(float), stream);

    k_cvt8<<<NROWS * PD / 8 / 256, 256, 0, stream>>>(predictor, pred8, 1.f, NROWS * PD / 8);
    k_cvt8<<<TOTD * PD / 8 / 256, 256, 0, stream>>>(W1, W1_8, 16.f, TOTD * PD / 8);
    k_cvt8<<<TOTD * TOTD / 8 / 256, 256, 0, stream>>>(W2, W2_8, 16.f, TOTD * TOTD / 8);
    k_tb<<<dim3(SIN / 32, SIN / 32), 256, 0, stream>>>(LS, LSTb);

    k_gemm1<<<16 * 256, 256, 0, stream>>>(pred8, W1_8, b1, Hraw8);
    k_ln<<<NROWS, 256, 0, stream>>>(Hraw8, H8, LSTb, cbidx, gamma, beta);
    k_gemm2<<<16 * 256, 256, 0, stream>>>(H8, W2_8, b2, cbidx, pm_, ps_, pt_);
    k_comb<<<NROWS * NCB / 256, 256, 0, stream>>>(pm_, ps_, pt_, cbidx, out);
}

// Round 9
// 538.176 us; speedup vs baseline: 1.2686x; 1.2241x over previous
//
#include <hip/hip_runtime.h>

#define NROWS 32768   // B*T
#define PD    512     // P_DIM
#define NCB   8       // NC
#define CSZ   256     // CS
#define TOTD  2048    // TOT
#define SIN   1792    // SELF_IN / SELF_OUT

typedef float floatx4  __attribute__((ext_vector_type(4)));
typedef float floatx16 __attribute__((ext_vector_type(16)));
typedef int   intx4    __attribute__((ext_vector_type(4)));
typedef int   intx8    __attribute__((ext_vector_type(8)));

__device__ __forceinline__ float bf2f(unsigned int h) {
    return __uint_as_float(h << 16);
}
__device__ __forceinline__ unsigned short f2bf(float f) {
    unsigned int u = __float_as_uint(f);
    u += 0x7FFFu + ((u >> 16) & 1u);
    return (unsigned short)(u >> 16);
}
// f32 -> fp8 e4m3 (single value, RNE, saturating)
__device__ __forceinline__ unsigned char f2fp8(float v) {
    int p = __builtin_amdgcn_cvt_pk_fp8_f32(v, v, 0, false);
    return (unsigned char)(p & 0xFF);
}

// async global->LDS, 16B per lane; LDS dest = wave-uniform base + lane*16
__device__ __forceinline__ void gload16(const unsigned char* g, unsigned char* l) {
    __builtin_amdgcn_global_load_lds(
        (const __attribute__((address_space(1))) void*)g,
        (__attribute__((address_space(3))) void*)l, 16, 0, 0);
}

// MFMA 32x32x64 f8f6f4 (cbsz=blgp=0 => e4m3 x e4m3), acc pinned to AGPRs so
// acc regs stay out of the arch-VGPR budget (round-2/3 spill lesson).
#define MFMA64(ACC, A, B)                                                     \
    asm volatile("v_mfma_f32_32x32x64_f8f6f4 %0, %1, %2, %0"                  \
                 : "+a"(ACC) : "v"(A), "v"(B))

#define SBAR() asm volatile("s_barrier" ::: "memory")

// ---------------- f32 -> fp8 conversion (8 elems/thread) ----------------
__global__ __launch_bounds__(256) void k_cvt8(const float* __restrict__ in,
                                              unsigned char* __restrict__ out,
                                              float scale, int n8) {
    int i = blockIdx.x * 256 + threadIdx.x;
    if (i >= n8) return;
    float4 a = ((const float4*)in)[2 * i];
    float4 b = ((const float4*)in)[2 * i + 1];
    int p0 = __builtin_amdgcn_cvt_pk_fp8_f32(a.x * scale, a.y * scale, 0, false);
    p0     = __builtin_amdgcn_cvt_pk_fp8_f32(a.z * scale, a.w * scale, p0, true);
    int p1 = __builtin_amdgcn_cvt_pk_fp8_f32(b.x * scale, b.y * scale, 0, false);
    p1     = __builtin_amdgcn_cvt_pk_fp8_f32(b.z * scale, b.w * scale, p1, true);
    int2 o; o.x = p0; o.y = p1;
    ((int2*)out)[i] = o;
}

// -------- transpose linear_self (1792x1792) f32 -> bf16, LSTb[in][out] --------
__global__ __launch_bounds__(256) void k_tb(const float* __restrict__ in,
                                            unsigned short* __restrict__ out) {
    __shared__ float t[32][33];
    int bx = blockIdx.x * 32, by = blockIdx.y * 32;
    int tx = threadIdx.x & 31, ty = threadIdx.x >> 5;
#pragma unroll
    for (int j = 0; j < 32; j += 8)
        t[ty + j][tx] = in[(size_t)(by + ty + j) * SIN + bx + tx];
    __syncthreads();
#pragma unroll
    for (int j = 0; j < 32; j += 8)
        out[(size_t)(bx + ty + j) * SIN + by + tx] = f2bf(t[tx][ty + j]);
}

// ROUND-4 SKELETON, verbatim (measured best: 285us gemm2 / 557.9 total).
// 128x128 tile, 256 thr / 4 waves, wave tile 64x64 (2x2 MFMA, acc 64 AGPR
// pinned), TRIPLE buffer, ONE barrier + vmcnt(4) per K-iter, prefetch dist 2.
// r5-r8 established: thin waves (325), 8-wave 256^2 (356), fat 256x128 (395),
// conflict-free planes + operand assembly (372) ALL regress. Do not touch.
//
// LDS layout per 8KB buffer (K=64 slab of 128 rows):
//   [tile T=row>>5 (4)][granule g (64)][32B]  byte = T*2048 + g*32
//   granule g holds row = T*32 + (sigma(g)&31), k bytes (g>>5)*32 .. +31,
//   sigma(g) = g ^ ((g&12)>>2)  (involution, mirrored write/read).
// Read: lane l loads intx8 at tilebase + ((l<<5) ^ ((l&12)<<3)) (two b128,
//   32B contiguous per lane -> feeds MFMA directly, no assembly movs).
//
// ONLY change this round: XCD-aware tile order. HW places bid on XCD bid%8;
// wg = (bid&7)*512 + (bid>>3) gives each XCD 512 consecutive wg. Decode wg
// COL-INNER (row0 = wg>>4, col0 = wg&15) so an XCD runs each H row-panel's
// 16 col-blocks back-to-back: H panel (256KB) L2-resident, W2 (4MB) ~L2.
// (r7's mapping was the inverse -- all rows per XCD -- FETCH 537MB, proving
// the mechanism with the wrong sign. Ideal here: ~70-110MB vs r4's 250MB.)

// ---------------- GEMM1 (fp8): Hraw8 = fp8(8 * (pred @ W1^T + b1)) ----------------
__global__ __launch_bounds__(256)
void k_gemm1(const unsigned char* __restrict__ A,
             const unsigned char* __restrict__ Bw,
             const float* __restrict__ bias,
             unsigned char* __restrict__ Out) {
    const int K = PD;
    __shared__ __align__(16) unsigned char As[3 * 8192];
    __shared__ __align__(16) unsigned char Bs[3 * 8192];

    const int tid  = threadIdx.x;
    const int lane = tid & 63;
    const int wave = tid >> 6;
    const int wm = (wave >> 1) << 6;
    const int wn = (wave & 1) << 6;
    const int wg   = (blockIdx.x & 7) * 512 + (blockIdx.x >> 3);
    const int row0 = (wg >> 4) << 7;
    const int col0 = (wg & 15) << 7;

    floatx16 acc00 = 0.f, acc01 = 0.f, acc10 = 0.f, acc11 = 0.f;

    const int lh    = lane >> 1;
    const int srow  = ((wave >> 1) << 5) + (lh ^ ((lh & 12) >> 2));
    const int skoff = ((wave & 1) << 5) + ((lane & 1) << 4);
    const unsigned char* Ag  = A  + (size_t)(row0 + srow) * K + skoff;
    const unsigned char* Ag2 = Ag + (size_t)64 * K;
    const unsigned char* Bg  = Bw + (size_t)(col0 + srow) * K + skoff;
    const unsigned char* Bg2 = Bg + (size_t)64 * K;
    unsigned char* Al = As + wave * 1024;
    unsigned char* Bl = Bs + wave * 1024;

    gload16(Ag,        Al);
    gload16(Ag2,       Al + 4096);
    gload16(Bg,        Bl);
    gload16(Bg2,       Bl + 4096);
    gload16(Ag + 64,   Al + 8192);
    gload16(Ag2 + 64,  Al + 8192 + 4096);
    gload16(Bg + 64,   Bl + 8192);
    gload16(Bg2 + 64,  Bl + 8192 + 4096);

    const int ro = (lane << 5) ^ ((lane & 12) << 3);

    auto compute = [&](int cbuf) {
        const unsigned char* Ab = As + cbuf * 8192 + ((wm >> 5) << 11) + ro;
        const unsigned char* Bb = Bs + cbuf * 8192 + ((wn >> 5) << 11) + ro;
        intx8 a0 = *(const intx8*)Ab;
        intx8 b0 = *(const intx8*)Bb;
        intx8 a1 = *(const intx8*)(Ab + 2048);
        intx8 b1 = *(const intx8*)(Bb + 2048);
        MFMA64(acc00, a0, b0);
        MFMA64(acc10, a1, b0);
        MFMA64(acc01, a0, b1);
        MFMA64(acc11, a1, b1);
    };

    const int NI = K / 64;   // 8
    int cb = 0, nb = 2;
    for (int i = 0; i < NI - 1; ++i) {
        asm volatile("s_waitcnt vmcnt(4)" ::: "memory");
        SBAR();
        if (i + 2 < NI) {
            const int k0 = (i + 2) * 64;
            gload16(Ag + k0,  Al + nb * 8192);
            gload16(Ag2 + k0, Al + nb * 8192 + 4096);
            gload16(Bg + k0,  Bl + nb * 8192);
            gload16(Bg2 + k0, Bl + nb * 8192 + 4096);
        }
        compute(cb);
        cb = (cb + 1 == 3) ? 0 : cb + 1;
        nb = (nb + 1 == 3) ? 0 : nb + 1;
    }
    asm volatile("s_waitcnt vmcnt(0)" ::: "memory");
    SBAR();
    compute(cb);
    asm volatile("s_nop 7\n\ts_nop 7\n\ts_nop 7" ::: "memory");  // MFMA->VALU read spacing

    // epilogue: hidden = acc/16 + b1; store fp8(8*hidden)
    const int l31  = lane & 31;
    const int half = lane >> 5;
    auto epi = [&](const floatx16& A0, const floatx16& A1, int mtoff) {
        const int col = col0 + wn + l31;
        const float bc0 = bias[col];
        const float bc1 = bias[col + 32];
#pragma unroll
        for (int r = 0; r < 16; ++r) {
            const int row = row0 + wm + mtoff + (r & 3) + ((r >> 2) << 3) + (half << 2);
            Out[(size_t)row * TOTD + col]      = f2fp8((A0[r] * 0.0625f + bc0) * 8.f);
            Out[(size_t)row * TOTD + col + 32] = f2fp8((A1[r] * 0.0625f + bc1) * 8.f);
        }
    };
    epi(acc00, acc01, 0);
    epi(acc10, acc11, 32);
}

// -------- fused: self-gather + relu + LayerNorm; fp8 in (x8) -> fp8 out (x8) --------
__global__ __launch_bounds__(256) void k_ln(const unsigned char* __restrict__ Hraw8,
                                            unsigned char* __restrict__ H8,
                                            const unsigned short* __restrict__ LSTb,
                                            const int* __restrict__ idx,
                                            const float* __restrict__ gamma,
                                            const float* __restrict__ beta) {
    const int row = blockIdx.x;
    const int tid = threadIdx.x;
    __shared__ int sidx[8];
    __shared__ float ws4[4], wss4[4];
    if (tid < 8) sidx[tid] = idx[(size_t)row * NCB + tid];

    uint2 w = ((const uint2*)(Hraw8 + (size_t)row * TOTD))[tid];
    float x[8];
    x[0] = __builtin_amdgcn_cvt_f32_fp8(w.x, 0) * 0.125f;
    x[1] = __builtin_amdgcn_cvt_f32_fp8(w.x, 1) * 0.125f;
    x[2] = __builtin_amdgcn_cvt_f32_fp8(w.x, 2) * 0.125f;
    x[3] = __builtin_amdgcn_cvt_f32_fp8(w.x, 3) * 0.125f;
    x[4] = __builtin_amdgcn_cvt_f32_fp8(w.y, 0) * 0.125f;
    x[5] = __builtin_amdgcn_cvt_f32_fp8(w.y, 1) * 0.125f;
    x[6] = __builtin_amdgcn_cvt_f32_fp8(w.y, 2) * 0.125f;
    x[7] = __builtin_amdgcn_cvt_f32_fp8(w.y, 3) * 0.125f;
    __syncthreads();

    const int gt = tid >> 5;
#pragma unroll
    for (int c = 0; c < 7; ++c) {
        if (c < gt) {
            int ic = sidx[c];
            if (ic >= 0) {
                uint4 v = *(const uint4*)(LSTb + (size_t)(c * CSZ + ic) * SIN + (tid * 8 - CSZ));
                x[0] += bf2f(v.x & 0xFFFF); x[1] += bf2f(v.x >> 16);
                x[2] += bf2f(v.y & 0xFFFF); x[3] += bf2f(v.y >> 16);
                x[4] += bf2f(v.z & 0xFFFF); x[5] += bf2f(v.z >> 16);
                x[6] += bf2f(v.w & 0xFFFF); x[7] += bf2f(v.w >> 16);
            }
        }
    }
#pragma unroll
    for (int e = 0; e < 8; ++e) x[e] = fmaxf(x[e], 0.f);

    float s = 0.f, ss = 0.f;
#pragma unroll
    for (int e = 0; e < 8; ++e) { s += x[e]; ss += x[e] * x[e]; }
#pragma unroll
    for (int o = 32; o; o >>= 1) { s += __shfl_xor(s, o); ss += __shfl_xor(ss, o); }
    if ((tid & 63) == 0) { ws4[tid >> 6] = s; wss4[tid >> 6] = ss; }
    __syncthreads();
    s  = ws4[0] + ws4[1] + ws4[2] + ws4[3];
    ss = wss4[0] + wss4[1] + wss4[2] + wss4[3];
    const float mu = s * (1.f / TOTD);
    const float var = ss * (1.f / TOTD) - mu * mu;
    const float rstd = rsqrtf(var + 1e-5f);
    float y[8];
#pragma unroll
    for (int e = 0; e < 8; ++e) {
        int col = tid * 8 + e;
        y[e] = ((x[e] - mu) * rstd * gamma[col] + beta[col]) * 8.f;   // H scale 8
    }
    int p0 = __builtin_amdgcn_cvt_pk_fp8_f32(y[0], y[1], 0, false);
    p0     = __builtin_amdgcn_cvt_pk_fp8_f32(y[2], y[3], p0, true);
    int p1 = __builtin_amdgcn_cvt_pk_fp8_f32(y[4], y[5], 0, false);
    p1     = __builtin_amdgcn_cvt_pk_fp8_f32(y[6], y[7], p1, true);
    int2 o; o.x = p0; o.y = p1;
    ((int2*)(H8 + (size_t)row * TOTD))[tid] = o;
}

// ------- GEMM2 (fp8): 128x128 tile, r4 pipeline + partial-softmax epilogue -------
__global__ __launch_bounds__(256)
void k_gemm2(const unsigned char* __restrict__ H,
             const unsigned char* __restrict__ W2,
             const float* __restrict__ b2,
             const int* __restrict__ idx,
             float* __restrict__ pm_,
             float* __restrict__ ps_,
             float* __restrict__ pt_) {
    const int K = TOTD;
    __shared__ __align__(16) unsigned char As[3 * 8192];
    __shared__ __align__(16) unsigned char Bs[3 * 8192];
    __shared__ int tidx[128];

    const int tid  = threadIdx.x;
    const int lane = tid & 63;
    const int wave = tid >> 6;
    const int wm = (wave >> 1) << 6;
    const int wn = (wave & 1) << 6;
    const int wg   = (blockIdx.x & 7) * 512 + (blockIdx.x >> 3);
    const int row0 = (wg >> 4) << 7;
    const int col0 = (wg & 15) << 7;
    const int g    = col0 >> 8;

    floatx16 acc00 = 0.f, acc01 = 0.f, acc10 = 0.f, acc11 = 0.f;

    const int lh    = lane >> 1;
    const int srow  = ((wave >> 1) << 5) + (lh ^ ((lh & 12) >> 2));
    const int skoff = ((wave & 1) << 5) + ((lane & 1) << 4);
    const unsigned char* Ag  = H  + (size_t)(row0 + srow) * K + skoff;
    const unsigned char* Ag2 = Ag + (size_t)64 * K;
    const unsigned char* Bg  = W2 + (size_t)(col0 + srow) * K + skoff;
    const unsigned char* Bg2 = Bg + (size_t)64 * K;
    unsigned char* Al = As + wave * 1024;
    unsigned char* Bl = Bs + wave * 1024;

    if (tid < 128) tidx[tid] = idx[(size_t)(row0 + tid) * NCB + g];

    gload16(Ag,        Al);
    gload16(Ag2,       Al + 4096);
    gload16(Bg,        Bl);
    gload16(Bg2,       Bl + 4096);
    gload16(Ag + 64,   Al + 8192);
    gload16(Ag2 + 64,  Al + 8192 + 4096);
    gload16(Bg + 64,   Bl + 8192);
    gload16(Bg2 + 64,  Bl + 8192 + 4096);

    const int ro = (lane << 5) ^ ((lane & 12) << 3);

    auto compute = [&](int cbuf) {
        const unsigned char* Ab = As + cbuf * 8192 + ((wm >> 5) << 11) + ro;
        const unsigned char* Bb = Bs + cbuf * 8192 + ((wn >> 5) << 11) + ro;
        intx8 a0 = *(const intx8*)Ab;
        intx8 b0 = *(const intx8*)Bb;
        intx8 a1 = *(const intx8*)(Ab + 2048);
        intx8 b1 = *(const intx8*)(Bb + 2048);
        MFMA64(acc00, a0, b0);
        MFMA64(acc10, a1, b0);
        MFMA64(acc01, a0, b1);
        MFMA64(acc11, a1, b1);
    };

    const int NI = K / 64;   // 32
    int cb = 0, nb = 2;
    for (int i = 0; i < NI - 1; ++i) {
        asm volatile("s_waitcnt vmcnt(4)" ::: "memory");
        SBAR();
        if (i + 2 < NI) {
            const int k0 = (i + 2) * 64;
            gload16(Ag + k0,  Al + nb * 8192);
            gload16(Ag2 + k0, Al + nb * 8192 + 4096);
            gload16(Bg + k0,  Bl + nb * 8192);
            gload16(Bg2 + k0, Bl + nb * 8192 + 4096);
        }
        compute(cb);
        cb = (cb + 1 == 3) ? 0 : cb + 1;
        nb = (nb + 1 == 3) ? 0 : nb + 1;
    }
    asm volatile("s_waitcnt vmcnt(0)" ::: "memory");
    SBAR();
    compute(cb);
    asm volatile("s_nop 7\n\ts_nop 7\n\ts_nop 7" ::: "memory");  // MFMA->VALU read spacing

    // ---- epilogue: per-row partials over this wave's 64-col window ----
    const int l31  = lane & 31;
    const int half = lane >> 5;
    const int slot = (col0 + wn) >> 6;   // 0..31
    const int coff = (col0 & 255) + wn;
    const float bc0 = b2[col0 + wn + l31];
    const float bc1 = b2[col0 + wn + 32 + l31];

    auto epi = [&](const floatx16& A0, const floatx16& A1, int mtoff) {
#pragma unroll
        for (int r = 0; r < 16; ++r) {
            const int lrow = wm + mtoff + (r & 3) + ((r >> 2) << 3) + (half << 2);
            const int ic   = tidx[lrow];
            const int tloc = ic - coff;
            float v0 = A0[r] * 0.0078125f + bc0;
            float v1 = A1[r] * 0.0078125f + bc1;
            float mm = fmaxf(v0, v1), tv = 0.f;
            if (ic >= 0) {
                if (l31 == tloc)      tv += v0;
                if (l31 + 32 == tloc) tv += v1;
            }
#pragma unroll
            for (int o = 1; o < 32; o <<= 1) mm = fmaxf(mm, __shfl_xor(mm, o));
            float sv = __expf(v0 - mm) + __expf(v1 - mm);
#pragma unroll
            for (int o = 1; o < 32; o <<= 1) { sv += __shfl_xor(sv, o); tv += __shfl_xor(tv, o); }
            if (l31 == 0) {
                const int row = row0 + lrow;
                pm_[(size_t)slot * NROWS + row] = mm;
                ps_[(size_t)slot * NROWS + row] = sv;
                pt_[(size_t)slot * NROWS + row] = tv;
            }
        }
    };
    epi(acc00, acc01, 0);
    epi(acc10, acc11, 32);
}

// ------- combine: merge 4 slots per (row, group), accumulate logprob + count -------
__global__ __launch_bounds__(256) void k_comb(const float* __restrict__ pm_,
                                              const float* __restrict__ ps_,
                                              const float* __restrict__ pt_,
                                              const int* __restrict__ idx,
                                              float* __restrict__ out) {
    const int i   = blockIdx.x * 256 + threadIdx.x;
    const int row = i & (NROWS - 1);
    const int g   = i >> 15;
    const int ic  = idx[(size_t)row * NCB + g];
    float lp = 0.f, cnt = 0.f;
    if (ic >= 0) {
        const size_t b = (size_t)(g * 4) * NROWS + row;
        float m0 = pm_[b], m1 = pm_[b + NROWS], m2 = pm_[b + 2 * NROWS], m3 = pm_[b + 3 * NROWS];
        float mm = fmaxf(fmaxf(m0, m1), fmaxf(m2, m3));
        float Z = ps_[b] * __expf(m0 - mm) + ps_[b + NROWS] * __expf(m1 - mm)
                + ps_[b + 2 * NROWS] * __expf(m2 - mm) + ps_[b + 3 * NROWS] * __expf(m3 - mm);
        float t = pt_[b] + pt_[b + NROWS] + pt_[b + 2 * NROWS] + pt_[b + 3 * NROWS];
        lp = t - (mm + __logf(Z));
        cnt = 1.f;
    }
#pragma unroll
    for (int o = 1; o < 64; o <<= 1) { lp += __shfl_xor(lp, o); cnt += __shfl_xor(cnt, o); }
    __shared__ float wred[8];
    const int lane = threadIdx.x & 63, wave = threadIdx.x >> 6;
    if (lane == 0) { wred[wave] = lp; wred[4 + wave] = cnt; }
    __syncthreads();
    if (threadIdx.x == 0) {
        atomicAdd(&out[0], wred[0] + wred[1] + wred[2] + wred[3]);
        atomicAdd(&out[1], wred[4] + wred[5] + wred[6] + wred[7]);
    }
}

extern "C" void kernel_launch(void* const* d_in, const int* in_sizes, int n_in,
                              void* d_out, int out_size, void* d_ws, size_t ws_size,
                              hipStream_t stream) {
    const float* predictor = (const float*)d_in[0];
    const int*   cbidx     = (const int*)d_in[1];
    const float* W1        = (const float*)d_in[2];
    const float* b1        = (const float*)d_in[3];
    const float* LS        = (const float*)d_in[4];
    const float* gamma     = (const float*)d_in[5];
    const float* beta      = (const float*)d_in[6];
    const float* W2        = (const float*)d_in[7];
    const float* b2        = (const float*)d_in[8];
    float* out = (float*)d_out;

    char* ws = (char*)d_ws;
    size_t off = 0;
    auto alloc = [&](size_t bytes) {
        char* p = ws + off;
        off += (bytes + 255) & ~(size_t)255;
        return p;
    };
    unsigned char* Hraw8 = (unsigned char*)alloc((size_t)NROWS * TOTD);   // dead after k_ln -> pm/ps/pt alias
    unsigned char* R2    = (unsigned char*)alloc((size_t)NROWS * TOTD);   // pred8+W1_8, then H8
    unsigned char* W2_8  = (unsigned char*)alloc((size_t)TOTD * TOTD);
    unsigned short* LSTb = (unsigned short*)alloc((size_t)SIN * SIN * 2);

    unsigned char* pred8 = R2;
    unsigned char* W1_8  = R2 + (size_t)NROWS * PD;
    unsigned char* H8    = R2;
    float* pm_ = (float*)Hraw8;
    float* ps_ = pm_ + (size_t)32 * NROWS;
    float* pt_ = ps_ + (size_t)32 * NROWS;

    hipMemsetAsync(d_out, 0, 2 * sizeof(float), stream);

    k_cvt8<<<NROWS * PD / 8 / 256, 256, 0, stream>>>(predictor, pred8, 1.f, NROWS * PD / 8);
    k_cvt8<<<TOTD * PD / 8 / 256, 256, 0, stream>>>(W1, W1_8, 16.f, TOTD * PD / 8);
    k_cvt8<<<TOTD * TOTD / 8 / 256, 256, 0, stream>>>(W2, W2_8, 16.f, TOTD * TOTD / 8);
    k_tb<<<dim3(SIN / 32, SIN / 32), 256, 0, stream>>>(LS, LSTb);

    k_gemm1<<<16 * 256, 256, 0, stream>>>(pred8, W1_8, b1, Hraw8);
    k_ln<<<NROWS, 256, 0, stream>>>(Hraw8, H8, LSTb, cbidx, gamma, beta);
    k_gemm2<<<16 * 256, 256, 0, stream>>>(H8, W2_8, b2, cbidx, pm_, ps_, pt_);
    k_comb<<<NROWS * NCB / 256, 256, 0, stream>>>(pm_, ps_, pt_, cbidx, out);
}